// Round 3
// baseline (454.326 us; speedup 1.0000x reference)
//
#include <hip/hip_runtime.h>

// MetapathGATConv fused kernel for MI355X (gfx950) — R6.
// R4: 201us @16 waves/CU; R5: 287us @16 waves/CU (regression). Root cause of
// both caps: unified VGPR+AGPR file -> combined 128 regs/wave (64 arch + 64
// acc) = 4 waves/EU. R5 additionally register-starved P1/P5 (b[8], 92+ regs
// needed) -> serialized global loads. R6: NB=4, 512 threads, lean per-wave
// GEMM tiles (P1 acc[2][4]=32 AGPR, P5 24 AGPR), __launch_bounds__(512,6)
// -> target 3 blocks/CU = 24 waves/CU; LDS 38.5KB no longer binds.

#define NNODES 16384
#define NB 4
#define MR 32              // rows per WG = NB*8

typedef _Float16 f16x8 __attribute__((ext_vector_type(8)));
typedef _Float16 f16x4 __attribute__((ext_vector_type(4)));
typedef _Float16 f16x2 __attribute__((ext_vector_type(2)));
typedef float f32x4 __attribute__((ext_vector_type(4)));

#if __has_builtin(__builtin_amdgcn_fdot2)
#define FDOT2(a, b, c) __builtin_amdgcn_fdot2((a), (b), (c), false)
#else
#define FDOT2(a, b, c) ((c) + (float)(a)[0] * (float)(b)[0] + (float)(a)[1] * (float)(b)[1])
#endif

__device__ __forceinline__ f16x2 leaky2(f16x2 t) {
#if __has_builtin(__builtin_elementwise_max)
    return __builtin_elementwise_max(t, t * (f16x2){(_Float16)0.2f, (_Float16)0.2f});
#else
    const unsigned u = __builtin_bit_cast(unsigned, t) & 0x7FFF7FFFu;
    const f16x2 at = __builtin_bit_cast(f16x2, u);
    return t * (f16x2){(_Float16)0.6f, (_Float16)0.6f} +
           at * (f16x2){(_Float16)0.4f, (_Float16)0.4f};
#endif
}
__device__ __forceinline__ f16x2 relu2(f16x2 t) {
#if __has_builtin(__builtin_elementwise_max)
    return __builtin_elementwise_max(t, (f16x2){(_Float16)0.f, (_Float16)0.f});
#else
    const unsigned u = __builtin_bit_cast(unsigned, t) & 0x7FFF7FFFu;
    const f16x2 at = __builtin_bit_cast(f16x2, u);
    return (t + at) * (f16x2){(_Float16)0.5f, (_Float16)0.5f};
#endif
}

// swizzled chunk address: buffers are [rows][32 chunks of 8 f16],
// chunk index XORed with (row&7) so column-strided accesses spread banks.
__device__ __forceinline__ int swz(int row, int chunk) {
    return row * 256 + ((chunk ^ (row & 7)) << 3);
}

// ---------------- weight prep: transpose+cast to f16 W^T[n][k] ----------------
// wt rows 0-255: Wl0^T | 256-511: Wr0^T | 512-767: Wl1^T | 768-1023: Wr1^T.
__global__ void prep_weights(const float* __restrict__ Wl0, const float* __restrict__ Wr0,
                             const float* __restrict__ Wl1, const float* __restrict__ Wr1,
                             _Float16* __restrict__ wt) {
    __shared__ float tile[64 * 68];   // 64x64 + pad 4
    const int t  = threadIdx.x;
    const int m  = blockIdx.x >> 4;
    const int kt = (blockIdx.x >> 2) & 3;
    const int nt = blockIdx.x & 3;
    const float* src = (m == 0 ? Wl0 : m == 1 ? Wr0 : m == 2 ? Wl1 : Wr1) + kt * 64 * 256;
    #pragma unroll
    for (int i = 0; i < 4; ++i) {
        const int idx = i * 256 + t;     // float4 id 0..1023
        const int kk  = idx >> 4;
        const int nn  = (idx & 15) * 4;
        const float4 v = *(const float4*)&src[kk * 256 + nt * 64 + nn];
        tile[kk * 68 + nn + 0] = v.x;
        tile[kk * 68 + nn + 1] = v.y;
        tile[kk * 68 + nn + 2] = v.z;
        tile[kk * 68 + nn + 3] = v.w;
    }
    __syncthreads();
    const int n  = t >> 2;
    const int ks = (t & 3) * 16;
    f16x8 o0, o1;
    #pragma unroll
    for (int e = 0; e < 8; ++e) o0[e] = (_Float16)tile[(ks + e) * 68 + n];
    #pragma unroll
    for (int e = 0; e < 8; ++e) o1[e] = (_Float16)tile[(ks + 8 + e) * 68 + n];
    _Float16* dst = &wt[(size_t)(m * 256 + nt * 64 + n) * 256 + kt * 64 + ks];
    *(f16x8*)dst = o0;
    *(f16x8*)(dst + 8) = o1;
}

__launch_bounds__(512, 6)
__global__ void gat_fused(const float* __restrict__ x,
                          const float* __restrict__ bl0, const float* __restrict__ br0,
                          const float* __restrict__ att0, const float* __restrict__ bias0,
                          const float* __restrict__ bl1, const float* __restrict__ br1,
                          const float* __restrict__ att1, const float* __restrict__ bias1,
                          const _Float16* __restrict__ wt,
                          float* __restrict__ out) {
    __shared__ _Float16 bufA[MR * 256];   // 16 KB: relu(x) -> xr0 -> h1
    __shared__ _Float16 bufB[MR * 256];   // 16 KB: xl0 -> xl1
    __shared__ _Float16 aw[MR * 4 * 8];   // 2 KB: alpha0 (f16)
    __shared__ _Float16 xrsH[NB * 256];   // 2 KB: xr_self (f16)
    __shared__ float lgs[NB * 32];        // 512 B: layer-1 logits
    __shared__ float al1[NB * 32];        // 512 B: alpha1
    __shared__ _Float16 attH[768];        // 1.5 KB: att0 | att1 | bias0 (f16)

    const int tid  = threadIdx.x;
    const int bg   = blockIdx.x;
    const int lane = tid & 63;
    const int wv   = tid >> 6;          // 0..7
    const int lr   = lane & 15;
    const int lq   = lane >> 4;

    // ---------------- P0: bufA = f16(relu(x)); cache att0/att1/bias0 as f16 ----------------
    {
        const float4* src = (const float4*)(x + (size_t)bg * (MR * 256));
        #pragma unroll
        for (int it = 0; it < 2; ++it) {
            const int g   = it * 512 + tid;   // 8-elem chunk id, 0..1023
            const int row = g >> 5;
            const int c   = g & 31;
            const float4 v0 = src[2 * g];
            const float4 v1 = src[2 * g + 1];
            f16x8 s;
            s[0] = (_Float16)fmaxf(v0.x, 0.f); s[1] = (_Float16)fmaxf(v0.y, 0.f);
            s[2] = (_Float16)fmaxf(v0.z, 0.f); s[3] = (_Float16)fmaxf(v0.w, 0.f);
            s[4] = (_Float16)fmaxf(v1.x, 0.f); s[5] = (_Float16)fmaxf(v1.y, 0.f);
            s[6] = (_Float16)fmaxf(v1.z, 0.f); s[7] = (_Float16)fmaxf(v1.w, 0.f);
            *(f16x8*)&bufA[swz(row, c)] = s;
        }
        if (tid < 256) {
            attH[tid]       = (_Float16)att0[tid];
            attH[512 + tid] = (_Float16)bias0[tid];
        } else {
            attH[tid]       = (_Float16)att1[tid - 256];   // att1 at [256..511]
        }
    }
    __syncthreads();

    // ---------------- P1: GEMM0 C[32][512] = relu(x) @ [Wl0|Wr0] ----------------
    // wave wv owns 64 N-cols (waves 0-3 -> xl/bufB, 4-7 -> xr/bufA), both M-tiles.
    // acc[2][4] = 32 AGPR; a[2]+b[4] keeps load pipeline within register budget.
    {
        f32x4 acc[2][4];
        #pragma unroll
        for (int m = 0; m < 2; ++m)
            #pragma unroll
            for (int n = 0; n < 4; ++n)
                acc[m][n] = f32x4{0.f, 0.f, 0.f, 0.f};
        #pragma unroll
        for (int kt = 0; kt < 8; ++kt) {
            f16x8 a[2], b[4];
            #pragma unroll
            for (int m = 0; m < 2; ++m)
                a[m] = *(const f16x8*)&bufA[swz(m * 16 + lr, kt * 4 + lq)];
            const int koff = kt * 32 + lq * 8;
            #pragma unroll
            for (int n = 0; n < 4; ++n)
                b[n] = *(const f16x8*)&wt[(size_t)(wv * 64 + n * 16 + lr) * 256 + koff];
            #pragma unroll
            for (int m = 0; m < 2; ++m)
                #pragma unroll
                for (int n = 0; n < 4; ++n)
                    acc[m][n] = __builtin_amdgcn_mfma_f32_16x16x32_f16(a[m], b[n], acc[m][n], 0, 0, 0);
        }
        __syncthreads();   // all A-reads of bufA done before xr overwrites it
        _Float16* dstbuf = (wv < 4) ? bufB : bufA;
        const float* bv = (wv < 4) ? bl0 : br0;
        #pragma unroll
        for (int n = 0; n < 4; ++n) {
            const int cl   = (wv & 3) * 64 + n * 16 + lr;   // 0..255 within dst buffer
            const float bias = bv[cl];
            const int ch   = cl >> 3, ce = cl & 7;
            #pragma unroll
            for (int m = 0; m < 2; ++m)
                #pragma unroll
                for (int r = 0; r < 4; ++r) {
                    const int row = m * 16 + lq * 4 + r;
                    dstbuf[swz(row, ch) + ce] = (_Float16)(acc[m][n][r] + bias);
                }
        }
    }
    __syncthreads();

    // ---------------- P2: layer-0 logits + softmax over j -> alpha0 (f16) ----------------
    // thread = (n, i, h, jh): 2 j-logits each. Depth-1 prefetch over cc
    // (1 xr + 1 att + 2 xl reads per step); i-dependent chunk rotation spreads banks.
    {
        const int n  = tid >> 7;          // node 0..3
        const int i  = (tid >> 4) & 7;
        const int h  = (tid >> 2) & 3;
        const int jh = tid & 3;           // j pair: {jh*2, jh*2+1}
        const int rowR = n * 8 + i;
        const int j0 = jh * 2, j1 = jh * 2 + 1;
        f16x8 xrb[2], ab[2], lb0[2], lb1[2];
        {
            const int c3 = (2 * h + i) & 7;
            xrb[0] = *(const f16x8*)&bufA[swz(rowR, h * 8 + c3)];
            ab[0]  = *(const f16x8*)&attH[h * 64 + c3 * 8];
            lb0[0] = *(const f16x8*)&bufB[swz(n * 8 + j0, h * 8 + c3)];
            lb1[0] = *(const f16x8*)&bufB[swz(n * 8 + j1, h * 8 + c3)];
        }
        float lgA = 0.f, lgB = 0.f;
        #pragma unroll
        for (int cc = 0; cc < 8; ++cc) {
            const int cur = cc & 1, nxt = cur ^ 1;
            if (cc < 7) {
                const int c3n = (cc + 1 + 2 * h + i) & 7;
                xrb[nxt] = *(const f16x8*)&bufA[swz(rowR, h * 8 + c3n)];
                ab[nxt]  = *(const f16x8*)&attH[h * 64 + c3n * 8];
                lb0[nxt] = *(const f16x8*)&bufB[swz(n * 8 + j0, h * 8 + c3n)];
                lb1[nxt] = *(const f16x8*)&bufB[swz(n * 8 + j1, h * 8 + c3n)];
            }
            const f16x8 x8 = xrb[cur];
            const f16x8 a8 = ab[cur];
            const f16x8 u8 = lb0[cur];
            const f16x8 w8 = lb1[cur];
            #pragma unroll
            for (int p = 0; p < 4; ++p) {
                const f16x2 xp = {x8[2 * p], x8[2 * p + 1]};
                const f16x2 apv = {a8[2 * p], a8[2 * p + 1]};
                const f16x2 t0 = leaky2(xp + f16x2{u8[2 * p], u8[2 * p + 1]});
                const f16x2 t1 = leaky2(xp + f16x2{w8[2 * p], w8[2 * p + 1]});
                lgA = FDOT2(t0, apv, lgA);
                lgB = FDOT2(t1, apv, lgB);
            }
        }
        // softmax over j (8 values spread across 4 lanes x 2 regs)
        float mx = fmaxf(lgA, lgB);
        mx = fmaxf(mx, __shfl_xor(mx, 1));
        mx = fmaxf(mx, __shfl_xor(mx, 2));
        const float exA = __expf(lgA - mx), exB = __expf(lgB - mx);
        float ssum = exA + exB;
        ssum += __shfl_xor(ssum, 1);
        ssum += __shfl_xor(ssum, 2);
        const float inv = 1.f / ssum;
        const f16x2 w = {(_Float16)(exA * inv), (_Float16)(exB * inv)};
        *(f16x2*)&aw[(rowR * 4 + h) * 8 + jh * 2] = w;
    }
    __syncthreads();

    // ---------------- P3: h1 = relu(alpha0 @ xl0 + bias0) -> bufA (packed f16) ----------------
    // thread = (row, h, q): 2 chunks (16 cols); j-loop depth-1 prefetch (2 reads).
    {
        const int row = tid >> 4;         // 0..31
        const int sub = tid & 15;
        const int h   = sub >> 2;
        const int q   = sub & 3;
        const int nn  = row >> 3;         // node 0..3
        const int cA  = h * 8 + ((q + 2 * h) & 7);
        const int cB  = h * 8 + ((q + 2 * h + 4) & 7);
        const f16x8 ah8 = *(const f16x8*)&aw[(row * 4 + h) * 8];
        f16x2 acc2[8];
        #pragma unroll
        for (int p = 0; p < 8; ++p) acc2[p] = (f16x2){(_Float16)0.f, (_Float16)0.f};
        f16x8 vb[2][2];
        vb[0][0] = *(const f16x8*)&bufB[swz(nn * 8, cA)];
        vb[0][1] = *(const f16x8*)&bufB[swz(nn * 8, cB)];
        #pragma unroll
        for (int j = 0; j < 8; ++j) {
            const int cur = j & 1, nxt = cur ^ 1;
            if (j < 7) {
                vb[nxt][0] = *(const f16x8*)&bufB[swz(nn * 8 + j + 1, cA)];
                vb[nxt][1] = *(const f16x8*)&bufB[swz(nn * 8 + j + 1, cB)];
            }
            const f16x2 a2 = {ah8[j], ah8[j]};
            #pragma unroll
            for (int k = 0; k < 2; ++k) {
                const f16x8 v = vb[cur][k];
                acc2[k * 4 + 0] += f16x2{v[0], v[1]} * a2;
                acc2[k * 4 + 1] += f16x2{v[2], v[3]} * a2;
                acc2[k * 4 + 2] += f16x2{v[4], v[5]} * a2;
                acc2[k * 4 + 3] += f16x2{v[6], v[7]} * a2;
            }
        }
        #pragma unroll
        for (int k = 0; k < 2; ++k) {
            const int c = k ? cB : cA;
            const f16x8 b8 = *(const f16x8*)&attH[512 + c * 8];
            f16x8 s;
            #pragma unroll
            for (int p = 0; p < 4; ++p) {
                const f16x2 r = relu2(acc2[k * 4 + p] + f16x2{b8[2 * p], b8[2 * p + 1]});
                s[2 * p]     = r[0];
                s[2 * p + 1] = r[1];
            }
            *(f16x8*)&bufA[swz(row, c)] = s;
        }
    }
    __syncthreads();

    // ---------------- P5: GEMM1: xl1 = h1@Wl1+bl1 -> bufB ; xrs = self@Wr1+br1 -> xrsH ----------------
    // accl[2][2]+accr[2] = 24 AGPR; 4 global B loads/kt.
    {
        f32x4 accl[2][2], accr[2];
        #pragma unroll
        for (int m = 0; m < 2; ++m)
            #pragma unroll
            for (int n = 0; n < 2; ++n)
                accl[m][n] = f32x4{0.f, 0.f, 0.f, 0.f};
        #pragma unroll
        for (int n = 0; n < 2; ++n) accr[n] = f32x4{0.f, 0.f, 0.f, 0.f};
        const _Float16* W1l = wt + 512 * 256;
        const _Float16* W1r = wt + 768 * 256;
        const int rowS = (lr & 3) * 8 + 7;    // self row of node (lr&3)
        #pragma unroll
        for (int kt = 0; kt < 8; ++kt) {
            const int koff = kt * 32 + lq * 8;
            f16x8 a[2], as, bl[2], br[2];
            #pragma unroll
            for (int m = 0; m < 2; ++m)
                a[m] = *(const f16x8*)&bufA[swz(m * 16 + lr, kt * 4 + lq)];
            as = *(const f16x8*)&bufA[swz(rowS, kt * 4 + lq)];
            #pragma unroll
            for (int n = 0; n < 2; ++n) {
                bl[n] = *(const f16x8*)&W1l[(size_t)(wv * 32 + n * 16 + lr) * 256 + koff];
                br[n] = *(const f16x8*)&W1r[(size_t)(wv * 32 + n * 16 + lr) * 256 + koff];
            }
            #pragma unroll
            for (int m = 0; m < 2; ++m)
                #pragma unroll
                for (int n = 0; n < 2; ++n)
                    accl[m][n] = __builtin_amdgcn_mfma_f32_16x16x32_f16(a[m], bl[n], accl[m][n], 0, 0, 0);
            #pragma unroll
            for (int n = 0; n < 2; ++n)
                accr[n] = __builtin_amdgcn_mfma_f32_16x16x32_f16(as, br[n], accr[n], 0, 0, 0);
        }
        // epilogue writes bufB (not read in P5) and xrsH
        #pragma unroll
        for (int n = 0; n < 2; ++n) {
            const int col = wv * 32 + n * 16 + lr;   // 0..255
            const float b1 = bl1[col], b2 = br1[col];
            const int ch = col >> 3, ce = col & 7;
            #pragma unroll
            for (int m = 0; m < 2; ++m)
                #pragma unroll
                for (int r = 0; r < 4; ++r) {
                    const int row = m * 16 + lq * 4 + r;
                    bufB[swz(row, ch) + ce] = (_Float16)(accl[m][n][r] + b1);
                }
            if (lq == 0) {
                #pragma unroll
                for (int r = 0; r < 4; ++r)          // D rows 0..3 = nodes 0..3
                    xrsH[r * 256 + col] = (_Float16)(accr[n][r] + b2);
            }
        }
    }
    __syncthreads();

    // ---------------- P6: layer-1 logits, softmax over r -> betas + alpha1 ----------------
    // 128 active threads; depth-1 prefetch (1 xrs + 1 xl1 + 1 att per step).
    {
        const int n  = tid >> 5;          // valid for tid<128: 0..3
        const int rr = (tid >> 2) & 7;
        const int h  = tid & 3;
        float lg = 0.f;
        if (tid < 128) {
            const int rowj = n * 8 + rr;
            f16x8 xbuf[2], lbuf[2], abuf[2];
            {
                const int c = h * 8 + ((2 * h) & 7);
                xbuf[0] = *(const f16x8*)&xrsH[n * 256 + c * 8];
                lbuf[0] = *(const f16x8*)&bufB[swz(rowj, c)];
                abuf[0] = *(const f16x8*)&attH[256 + c * 8];
            }
            #pragma unroll
            for (int cc = 0; cc < 8; ++cc) {
                const int cur = cc & 1, nxt = cur ^ 1;
                if (cc < 7) {
                    const int cn = h * 8 + ((cc + 1 + 2 * h) & 7);
                    xbuf[nxt] = *(const f16x8*)&xrsH[n * 256 + cn * 8];
                    lbuf[nxt] = *(const f16x8*)&bufB[swz(rowj, cn)];
                    abuf[nxt] = *(const f16x8*)&attH[256 + cn * 8];
                }
                const f16x8 x8 = xbuf[cur];
                const f16x8 l8 = lbuf[cur];
                const f16x8 a8 = abuf[cur];
                #pragma unroll
                for (int p = 0; p < 4; ++p) {
                    const f16x2 xp = {x8[2 * p], x8[2 * p + 1]};
                    const f16x2 lp = {l8[2 * p], l8[2 * p + 1]};
                    const f16x2 ap = {a8[2 * p], a8[2 * p + 1]};
                    const f16x2 t = leaky2(xp + lp);
                    lg = FDOT2(t, ap, lg);
                }
            }
            lgs[tid] = lg;
        }
        __syncthreads();
        if (tid < 128) {
            float M = -1e30f;
            float l[8];
            #pragma unroll
            for (int j = 0; j < 8; ++j) {
                l[j] = lgs[n * 32 + j * 4 + h];
                M = fmaxf(M, l[j]);
            }
            float S = 0.f;
            #pragma unroll
            for (int j = 0; j < 8; ++j) S += __expf(l[j] - M);
            const float a = __expf(lg - M) / S;
            al1[tid] = a;
            out[(size_t)NNODES * 256 + (size_t)(bg * NB + n) * 32 + rr * 4 + h] = a;  // betas
        }
    }
    __syncthreads();

    // ---------------- P7: out = relu(alpha1 @ xl1 + bias1) — all reads hoisted ----------------
    // thread = (node, col-pair): 2 output cols.
    {
        const int n  = tid >> 7;          // node 0..3
        const int q  = tid & 127;         // col pair id; cols 2q, 2q+1
        const int c0 = q * 2;
        const int h  = q >> 5;            // head = c0/64
        f16x2 v[8];
        float a[8];
        #pragma unroll
        for (int r = 0; r < 8; ++r) {
            v[r] = *(const f16x2*)&bufB[swz(n * 8 + r, q >> 2) + (q & 3) * 2];
            a[r] = al1[n * 32 + r * 4 + h];
        }
        float o0 = 0.f, o1 = 0.f;
        #pragma unroll
        for (int r = 0; r < 8; ++r) {
            o0 = fmaf((float)v[r][0], a[r], o0);
            o1 = fmaf((float)v[r][1], a[r], o1);
        }
        float2 res;
        res.x = fmaxf(o0 + bias1[c0 + 0], 0.f);
        res.y = fmaxf(o1 + bias1[c0 + 1], 0.f);
        *(float2*)&out[(size_t)(bg * NB + n) * 256 + c0] = res;
    }
}

extern "C" void kernel_launch(void* const* d_in, const int* in_sizes, int n_in,
                              void* d_out, int out_size, void* d_ws, size_t ws_size,
                              hipStream_t stream) {
    const float* x     = (const float*)d_in[0];
    const float* Wl0   = (const float*)d_in[1];
    const float* bl0   = (const float*)d_in[2];
    const float* Wr0   = (const float*)d_in[3];
    const float* br0   = (const float*)d_in[4];
    const float* att0  = (const float*)d_in[5];
    const float* bias0 = (const float*)d_in[6];
    const float* Wl1   = (const float*)d_in[7];
    const float* bl1   = (const float*)d_in[8];
    const float* Wr1   = (const float*)d_in[9];
    const float* br1   = (const float*)d_in[10];
    const float* att1  = (const float*)d_in[11];
    const float* bias1 = (const float*)d_in[12];
    _Float16* wt = (_Float16*)d_ws;   // 512 KB
    float* out = (float*)d_out;

    prep_weights<<<64, 256, 0, stream>>>(Wl0, Wr0, Wl1, Wr1, wt);
    gat_fused<<<NNODES / NB, 512, 0, stream>>>(x, bl0, br0, att0, bias0,
                                               bl1, br1, att1, bias1, wt, out);
}

// Round 4
// 357.705 us; speedup vs baseline: 1.2701x; 1.2701x over previous
//
#include <hip/hip_runtime.h>

// MetapathGATConv fused kernel for MI355X (gfx950) — R7.
// R4=201us, R5=287us, R6=313us. Post-mortem: WRITE_SIZE (logical ~19MB) was
// 75/63/214 MB -> scratch spill traffic. All variants sat at or over the
// combined VGPR+AGPR cap (unified file on gfx950). R7 = R4 structure (proven
// best: MR=64, 512 thr, 2048 blocks, launch_bounds(512,4), cap 128) with true
// pressure reduced below cap: P2 loses the xr2[32] preload (32 V live ->
// depth-1 pipelined like the other streams), P1/P5 narrow the A-operand
// working set (one `a` per m-tile). Expect WRITE_SIZE ~25MB, no spills.

#define NNODES 16384
#define NB 8
#define MR 64              // rows per WG = NB*8

typedef _Float16 f16x8 __attribute__((ext_vector_type(8)));
typedef _Float16 f16x4 __attribute__((ext_vector_type(4)));
typedef _Float16 f16x2 __attribute__((ext_vector_type(2)));
typedef float f32x4 __attribute__((ext_vector_type(4)));

#if __has_builtin(__builtin_amdgcn_fdot2)
#define FDOT2(a, b, c) __builtin_amdgcn_fdot2((a), (b), (c), false)
#else
#define FDOT2(a, b, c) ((c) + (float)(a)[0] * (float)(b)[0] + (float)(a)[1] * (float)(b)[1])
#endif

// cvt_pkrtz returns __fp16x2; bit_cast to our f16x2
__device__ __forceinline__ f16x2 pk2(float a, float b) {
    return __builtin_bit_cast(f16x2, __builtin_amdgcn_cvt_pkrtz(a, b));
}

__device__ __forceinline__ f16x2 leaky2(f16x2 t) {
#if __has_builtin(__builtin_elementwise_max)
    return __builtin_elementwise_max(t, t * (f16x2){(_Float16)0.2f, (_Float16)0.2f});
#else
    const unsigned u = __builtin_bit_cast(unsigned, t) & 0x7FFF7FFFu;
    const f16x2 at = __builtin_bit_cast(f16x2, u);
    return t * (f16x2){(_Float16)0.6f, (_Float16)0.6f} +
           at * (f16x2){(_Float16)0.4f, (_Float16)0.4f};
#endif
}
__device__ __forceinline__ f16x2 relu2(f16x2 t) {
#if __has_builtin(__builtin_elementwise_max)
    return __builtin_elementwise_max(t, (f16x2){(_Float16)0.f, (_Float16)0.f});
#else
    const unsigned u = __builtin_bit_cast(unsigned, t) & 0x7FFF7FFFu;
    const f16x2 at = __builtin_bit_cast(f16x2, u);
    return (t + at) * (f16x2){(_Float16)0.5f, (_Float16)0.5f};
#endif
}

// swizzled chunk address: buffers are [rows][32 chunks of 8 f16],
// chunk index XORed with (row&7) so column-strided accesses spread banks.
__device__ __forceinline__ int swz(int row, int chunk) {
    return row * 256 + ((chunk ^ (row & 7)) << 3);
}

// ---------------- weight prep: transpose+cast to f16 W^T[n][k] ----------------
// wt rows 0-255: Wl0^T | 256-511: Wr0^T | 512-767: Wl1^T | 768-1023: Wr1^T.
__global__ void prep_weights(const float* __restrict__ Wl0, const float* __restrict__ Wr0,
                             const float* __restrict__ Wl1, const float* __restrict__ Wr1,
                             _Float16* __restrict__ wt) {
    __shared__ float tile[64 * 68];   // 64x64 + pad 4
    const int t  = threadIdx.x;
    const int m  = blockIdx.x >> 4;
    const int kt = (blockIdx.x >> 2) & 3;
    const int nt = blockIdx.x & 3;
    const float* src = (m == 0 ? Wl0 : m == 1 ? Wr0 : m == 2 ? Wl1 : Wr1) + kt * 64 * 256;
    #pragma unroll
    for (int i = 0; i < 4; ++i) {
        const int idx = i * 256 + t;     // float4 id 0..1023
        const int kk  = idx >> 4;
        const int nn  = (idx & 15) * 4;
        const float4 v = *(const float4*)&src[kk * 256 + nt * 64 + nn];
        tile[kk * 68 + nn + 0] = v.x;
        tile[kk * 68 + nn + 1] = v.y;
        tile[kk * 68 + nn + 2] = v.z;
        tile[kk * 68 + nn + 3] = v.w;
    }
    __syncthreads();
    const int n  = t >> 2;
    const int ks = (t & 3) * 16;
    f16x8 o0, o1;
    #pragma unroll
    for (int e = 0; e < 8; ++e) o0[e] = (_Float16)tile[(ks + e) * 68 + n];
    #pragma unroll
    for (int e = 0; e < 8; ++e) o1[e] = (_Float16)tile[(ks + 8 + e) * 68 + n];
    _Float16* dst = &wt[(size_t)(m * 256 + nt * 64 + n) * 256 + kt * 64 + ks];
    *(f16x8*)dst = o0;
    *(f16x8*)(dst + 8) = o1;
}

__launch_bounds__(512, 4)
__global__ void gat_fused(const float* __restrict__ x,
                          const float* __restrict__ bl0, const float* __restrict__ br0,
                          const float* __restrict__ att0, const float* __restrict__ bias0,
                          const float* __restrict__ bl1, const float* __restrict__ br1,
                          const float* __restrict__ att1, const float* __restrict__ bias1,
                          const _Float16* __restrict__ wt,
                          float* __restrict__ out) {
    __shared__ _Float16 bufA[MR * 256];  // 32 KB: relu(x) -> xr0 -> h1
    __shared__ _Float16 bufB[MR * 256];  // 32 KB: xl0 -> xl1
    __shared__ float attbuf[2304];       // 9 KB: [0..2047] alpha0 -> xrs(f32) -> alpha1(0..255)
                                         //       [2048..2303] logits1
    __shared__ _Float16 attH[768];       // 1.5 KB: att0 | att1 | bias0 (f16)

    const int tid  = threadIdx.x;
    const int bg   = blockIdx.x;
    const int lane = tid & 63;
    const int wv   = tid >> 6;          // 0..7
    const int lr   = lane & 15;
    const int lq   = lane >> 4;

    // ---------------- P0: bufA = f16(relu(x)); cache att0/att1/bias0 as f16 ----------------
    {
        const float4* src = (const float4*)(x + (size_t)bg * (MR * 256));
        #pragma unroll
        for (int it = 0; it < 4; ++it) {
            const int g   = it * 512 + tid;   // 8-elem chunk id, 0..2047
            const int row = g >> 5;
            const int c   = g & 31;
            const float4 v0 = src[2 * g];
            const float4 v1 = src[2 * g + 1];
            f16x8 s;
            s[0] = (_Float16)fmaxf(v0.x, 0.f); s[1] = (_Float16)fmaxf(v0.y, 0.f);
            s[2] = (_Float16)fmaxf(v0.z, 0.f); s[3] = (_Float16)fmaxf(v0.w, 0.f);
            s[4] = (_Float16)fmaxf(v1.x, 0.f); s[5] = (_Float16)fmaxf(v1.y, 0.f);
            s[6] = (_Float16)fmaxf(v1.z, 0.f); s[7] = (_Float16)fmaxf(v1.w, 0.f);
            *(f16x8*)&bufA[swz(row, c)] = s;
        }
        if (tid < 256) {
            attH[tid]       = (_Float16)att0[tid];
            attH[512 + tid] = (_Float16)bias0[tid];
        } else {
            attH[tid]       = (_Float16)att1[tid - 256];   // att1 at [256..511]
        }
    }
    __syncthreads();

    // ---------------- P1: GEMM0 C[64][512] = relu(x) @ [Wl0|Wr0] ----------------
    // wave wv owns 64 N-cols (waves 0-3 -> xl/bufB, 4-7 -> xr/bufA), all 4 M-tiles.
    // A loaded one m-tile at a time to keep V-pressure under the 64-V budget
    // that coexists with the 64-AGPR accumulator (no spills).
    {
        f32x4 acc[4][4];
        #pragma unroll
        for (int m = 0; m < 4; ++m)
            #pragma unroll
            for (int n = 0; n < 4; ++n)
                acc[m][n] = f32x4{0.f, 0.f, 0.f, 0.f};
        #pragma unroll
        for (int kt = 0; kt < 8; ++kt) {
            const int koff = kt * 32 + lq * 8;
            f16x8 b[4];
            #pragma unroll
            for (int n = 0; n < 4; ++n)
                b[n] = *(const f16x8*)&wt[(size_t)(wv * 64 + n * 16 + lr) * 256 + koff];
            #pragma unroll
            for (int m = 0; m < 4; ++m) {
                const f16x8 a = *(const f16x8*)&bufA[swz(m * 16 + lr, kt * 4 + lq)];
                #pragma unroll
                for (int n = 0; n < 4; ++n)
                    acc[m][n] = __builtin_amdgcn_mfma_f32_16x16x32_f16(a, b[n], acc[m][n], 0, 0, 0);
            }
        }
        __syncthreads();   // all A-reads of bufA done before xr overwrites it
        _Float16* dstbuf = (wv < 4) ? bufB : bufA;
        const float* bv = (wv < 4) ? bl0 : br0;
        #pragma unroll
        for (int n = 0; n < 4; ++n) {
            const int cl   = (wv & 3) * 64 + n * 16 + lr;   // 0..255 within dst buffer
            const float bias = bv[cl];
            const int ch   = cl >> 3, ce = cl & 7;
            #pragma unroll
            for (int m = 0; m < 4; ++m)
                #pragma unroll
                for (int r = 0; r < 4; ++r) {
                    const int row = m * 16 + lq * 4 + r;
                    dstbuf[swz(row, ch) + ce] = (_Float16)(acc[m][n][r] + bias);
                }
        }
    }
    __syncthreads();

    // ---------------- P2: layer-0 logits + softmax over j -> alpha0 ----------------
    // thread = (n, i, h, jh): 4 j-logits. Depth-1 prefetch over cc: issue the
    // 6 reads (1 xr + 1 att + 4 xl) for cc+1 before computing cc. xr is in the
    // pipeline (NOT preloaded as xr2[32] — that 32-V spike caused spills).
    {
        const int n  = tid >> 6;          // node 0..7
        const int i  = (tid >> 3) & 7;
        const int h  = (tid >> 1) & 3;
        const int jh = tid & 1;
        const int rowR = n * 8 + i;
        f16x8 xrb[2], abuf[2], lbuf[2][4];
        {
            const int c3 = (2 * h) & 7;
            xrb[0]  = *(const f16x8*)&bufA[swz(rowR, h * 8 + c3)];
            abuf[0] = *(const f16x8*)&attH[h * 64 + c3 * 8];
            #pragma unroll
            for (int jj = 0; jj < 4; ++jj)
                lbuf[0][jj] = *(const f16x8*)&bufB[swz(n * 8 + jh * 4 + jj, h * 8 + c3)];
        }
        float lg[4] = {0.f, 0.f, 0.f, 0.f};
        #pragma unroll
        for (int cc = 0; cc < 8; ++cc) {
            const int cur = cc & 1, nxt = cur ^ 1;
            if (cc < 7) {
                const int c3n = (cc + 1 + 2 * h) & 7;
                xrb[nxt]  = *(const f16x8*)&bufA[swz(rowR, h * 8 + c3n)];
                abuf[nxt] = *(const f16x8*)&attH[h * 64 + c3n * 8];
                #pragma unroll
                for (int jj = 0; jj < 4; ++jj)
                    lbuf[nxt][jj] = *(const f16x8*)&bufB[swz(n * 8 + jh * 4 + jj, h * 8 + c3n)];
            }
            const f16x8 x8 = xrb[cur];
            const f16x2 x2[4] = {{x8[0], x8[1]}, {x8[2], x8[3]}, {x8[4], x8[5]}, {x8[6], x8[7]}};
            const f16x8 a8 = abuf[cur];
            const f16x2 a2[4] = {{a8[0], a8[1]}, {a8[2], a8[3]}, {a8[4], a8[5]}, {a8[6], a8[7]}};
            #pragma unroll
            for (int jj = 0; jj < 4; ++jj) {
                const f16x8 l8 = lbuf[cur][jj];
                const f16x2 l2[4] = {{l8[0], l8[1]}, {l8[2], l8[3]}, {l8[4], l8[5]}, {l8[6], l8[7]}};
                #pragma unroll
                for (int p = 0; p < 4; ++p) {
                    const f16x2 t = leaky2(x2[p] + l2[p]);
                    lg[jj] = FDOT2(t, a2[p], lg[jj]);
                }
            }
        }
        float mx = fmaxf(fmaxf(lg[0], lg[1]), fmaxf(lg[2], lg[3]));
        mx = fmaxf(mx, __shfl_xor(mx, 1));
        float ex[4], ssum = 0.f;
        #pragma unroll
        for (int jj = 0; jj < 4; ++jj) { ex[jj] = __expf(lg[jj] - mx); ssum += ex[jj]; }
        const float tot = ssum + __shfl_xor(ssum, 1);
        const float inv = 1.f / tot;
        #pragma unroll
        for (int jj = 0; jj < 4; ++jj)
            attbuf[((n * 8 + i) * 4 + h) * 8 + jh * 4 + jj] = ex[jj] * inv;
    }
    __syncthreads();

    // ---------------- P3: h1 = relu(alpha0 @ xl0 + bias0) -> bufA (packed f16) ----------------
    // thread = (row, h, half): 32 output cols; j-loop double-buffered (prefetch j+1's 4 reads).
    {
        const int row  = tid >> 3;        // 0..63
        const int sub  = tid & 7;
        const int h    = sub >> 1;
        const int half = sub & 1;
        const int nn   = row >> 3;
        const int cb   = h * 8 + half * 4;
        _Float16 ahv[8];
        #pragma unroll
        for (int j = 0; j < 8; ++j) ahv[j] = (_Float16)attbuf[(row * 4 + h) * 8 + j];
        f16x2 acc2[16];
        #pragma unroll
        for (int p = 0; p < 16; ++p) acc2[p] = (f16x2){(_Float16)0.f, (_Float16)0.f};
        f16x8 vbuf[2][4];
        #pragma unroll
        for (int cc = 0; cc < 4; ++cc)
            vbuf[0][cc] = *(const f16x8*)&bufB[swz(nn * 8, cb + ((cc + h) & 3))];
        #pragma unroll
        for (int j = 0; j < 8; ++j) {
            const int cur = j & 1, nxt = cur ^ 1;
            if (j < 7) {
                #pragma unroll
                for (int cc = 0; cc < 4; ++cc)
                    vbuf[nxt][cc] = *(const f16x8*)&bufB[swz(nn * 8 + j + 1, cb + ((cc + h) & 3))];
            }
            const f16x2 a2 = {ahv[j], ahv[j]};
            #pragma unroll
            for (int cc = 0; cc < 4; ++cc) {
                const f16x8 v = vbuf[cur][cc];
                acc2[cc * 4 + 0] += f16x2{v[0], v[1]} * a2;
                acc2[cc * 4 + 1] += f16x2{v[2], v[3]} * a2;
                acc2[cc * 4 + 2] += f16x2{v[4], v[5]} * a2;
                acc2[cc * 4 + 3] += f16x2{v[6], v[7]} * a2;
            }
        }
        #pragma unroll
        for (int cc = 0; cc < 4; ++cc) {
            const int c = cb + ((cc + h) & 3);
            const f16x8 b8 = *(const f16x8*)&attH[512 + c * 8];
            f16x8 s;
            #pragma unroll
            for (int p = 0; p < 4; ++p) {
                const f16x2 r = relu2(acc2[cc * 4 + p] + f16x2{b8[2 * p], b8[2 * p + 1]});
                s[2 * p]     = r[0];
                s[2 * p + 1] = r[1];
            }
            *(f16x8*)&bufA[swz(row, c)] = s;
        }
    }
    __syncthreads();

    // ---------------- P5: GEMM1: xl1 = h1@Wl1+bl1 -> bufB ; xrs = self@Wr1+br1 -> attbuf ----------------
    {
        f32x4 accl[4][2], accr[2];
        #pragma unroll
        for (int m = 0; m < 4; ++m)
            #pragma unroll
            for (int n = 0; n < 2; ++n)
                accl[m][n] = f32x4{0.f, 0.f, 0.f, 0.f};
        #pragma unroll
        for (int n = 0; n < 2; ++n) accr[n] = f32x4{0.f, 0.f, 0.f, 0.f};
        const _Float16* W1l = wt + 512 * 256;
        const _Float16* W1r = wt + 768 * 256;
        const int rowS = (lr & 7) * 8 + 7;    // self row of node (lr&7)
        #pragma unroll
        for (int kt = 0; kt < 8; ++kt) {
            const int koff = kt * 32 + lq * 8;
            f16x8 bl[2], br[2];
            #pragma unroll
            for (int n = 0; n < 2; ++n) {
                bl[n] = *(const f16x8*)&W1l[(size_t)(wv * 32 + n * 16 + lr) * 256 + koff];
                br[n] = *(const f16x8*)&W1r[(size_t)(wv * 32 + n * 16 + lr) * 256 + koff];
            }
            const f16x8 as = *(const f16x8*)&bufA[swz(rowS, kt * 4 + lq)];
            #pragma unroll
            for (int n = 0; n < 2; ++n)
                accr[n] = __builtin_amdgcn_mfma_f32_16x16x32_f16(as, br[n], accr[n], 0, 0, 0);
            #pragma unroll
            for (int m = 0; m < 4; ++m) {
                const f16x8 a = *(const f16x8*)&bufA[swz(m * 16 + lr, kt * 4 + lq)];
                #pragma unroll
                for (int n = 0; n < 2; ++n)
                    accl[m][n] = __builtin_amdgcn_mfma_f32_16x16x32_f16(a, bl[n], accl[m][n], 0, 0, 0);
            }
        }
        // epilogue writes bufB (not read in P5) and attbuf[0..2047] (alpha0 dead)
        #pragma unroll
        for (int n = 0; n < 2; ++n) {
            const int col = wv * 32 + n * 16 + lr;   // 0..255
            const float b1 = bl1[col], b2 = br1[col];
            const int ch = col >> 3, ce = col & 7;
            #pragma unroll
            for (int m = 0; m < 4; ++m)
                #pragma unroll
                for (int r = 0; r < 4; ++r) {
                    const int row = m * 16 + lq * 4 + r;
                    bufB[swz(row, ch) + ce] = (_Float16)(accl[m][n][r] + b1);
                }
            if (lq < 2) {
                #pragma unroll
                for (int r = 0; r < 4; ++r) {        // D rows 0..7 = nodes 0..7
                    const int node = lq * 4 + r;
                    attbuf[node * 256 + col] = accr[n][r] + b2;   // xrs, f32
                }
            }
        }
    }
    __syncthreads();

    // ---------------- P6: layer-1 logits, softmax over r -> betas + alpha1 ----------------
    // Depth-1 prefetch over cc (2 xrs float4 + 1 xl1 + 1 att per step).
    {
        const int n  = tid >> 5;
        const int rr = (tid >> 2) & 7;
        const int h  = tid & 3;
        float lg = 0.f;
        if (tid < 256) {
            const int rowj = n * 8 + rr;
            float4 xbuf0[2], xbuf1[2];
            f16x8 lbuf[2], abuf[2];
            {
                const int c = h * 8 + ((2 * h) & 7);
                xbuf0[0] = *(const float4*)&attbuf[n * 256 + c * 8];
                xbuf1[0] = *(const float4*)&attbuf[n * 256 + c * 8 + 4];
                lbuf[0]  = *(const f16x8*)&bufB[swz(rowj, c)];
                abuf[0]  = *(const f16x8*)&attH[256 + c * 8];
            }
            #pragma unroll
            for (int cc = 0; cc < 8; ++cc) {
                const int cur = cc & 1, nxt = cur ^ 1;
                if (cc < 7) {
                    const int cn = h * 8 + ((cc + 1 + 2 * h) & 7);
                    xbuf0[nxt] = *(const float4*)&attbuf[n * 256 + cn * 8];
                    xbuf1[nxt] = *(const float4*)&attbuf[n * 256 + cn * 8 + 4];
                    lbuf[nxt]  = *(const f16x8*)&bufB[swz(rowj, cn)];
                    abuf[nxt]  = *(const f16x8*)&attH[256 + cn * 8];
                }
                const float4 r0 = xbuf0[cur], r1 = xbuf1[cur];
                const f16x2 x2[4] = {pk2(r0.x, r0.y), pk2(r0.z, r0.w),
                                     pk2(r1.x, r1.y), pk2(r1.z, r1.w)};
                const f16x8 l8 = lbuf[cur];
                const f16x2 l2[4] = {{l8[0], l8[1]}, {l8[2], l8[3]}, {l8[4], l8[5]}, {l8[6], l8[7]}};
                const f16x8 a8 = abuf[cur];
                const f16x2 a2[4] = {{a8[0], a8[1]}, {a8[2], a8[3]}, {a8[4], a8[5]}, {a8[6], a8[7]}};
                #pragma unroll
                for (int p = 0; p < 4; ++p) {
                    const f16x2 t = leaky2(x2[p] + l2[p]);
                    lg = FDOT2(t, a2[p], lg);
                }
            }
        }
        __syncthreads();   // xrs reads done
        if (tid < 256) attbuf[2048 + tid] = lg;
        __syncthreads();
        if (tid < 256) {
            float M = -1e30f;
            float l[8];
            #pragma unroll
            for (int j = 0; j < 8; ++j) {
                l[j] = attbuf[2048 + n * 32 + j * 4 + h];
                M = fmaxf(M, l[j]);
            }
            float S = 0.f;
            #pragma unroll
            for (int j = 0; j < 8; ++j) S += __expf(l[j] - M);
            const float a = __expf(lg - M) / S;
            attbuf[tid] = a;    // alpha1 in [0..255] (xrs dead)
            out[(size_t)NNODES * 256 + (size_t)(bg * NB + n) * 32 + rr * 4 + h] = a;  // betas
        }
    }
    __syncthreads();

    // ---------------- P7: out = relu(alpha1 @ xl1 + bias1) — all reads hoisted ----------------
    {
        const int n  = tid >> 6;          // node 0..7
        const int q  = tid & 63;
        const int c0 = q * 4;
        const int h  = q >> 4;
        f16x4 v[8];
        float a[8];
        #pragma unroll
        for (int r = 0; r < 8; ++r) {
            v[r] = *(const f16x4*)&bufB[swz(n * 8 + r, q >> 1) + (q & 1) * 4];
            a[r] = attbuf[n * 32 + r * 4 + h];
        }
        float o0 = 0.f, o1 = 0.f, o2 = 0.f, o3 = 0.f;
        #pragma unroll
        for (int r = 0; r < 8; ++r) {
            o0 = fmaf((float)v[r][0], a[r], o0);
            o1 = fmaf((float)v[r][1], a[r], o1);
            o2 = fmaf((float)v[r][2], a[r], o2);
            o3 = fmaf((float)v[r][3], a[r], o3);
        }
        float4 res;
        res.x = fmaxf(o0 + bias1[c0 + 0], 0.f);
        res.y = fmaxf(o1 + bias1[c0 + 1], 0.f);
        res.z = fmaxf(o2 + bias1[c0 + 2], 0.f);
        res.w = fmaxf(o3 + bias1[c0 + 3], 0.f);
        *(float4*)&out[(size_t)(bg * NB + n) * 256 + c0] = res;
    }
}

extern "C" void kernel_launch(void* const* d_in, const int* in_sizes, int n_in,
                              void* d_out, int out_size, void* d_ws, size_t ws_size,
                              hipStream_t stream) {
    const float* x     = (const float*)d_in[0];
    const float* Wl0   = (const float*)d_in[1];
    const float* bl0   = (const float*)d_in[2];
    const float* Wr0   = (const float*)d_in[3];
    const float* br0   = (const float*)d_in[4];
    const float* att0  = (const float*)d_in[5];
    const float* bias0 = (const float*)d_in[6];
    const float* Wl1   = (const float*)d_in[7];
    const float* bl1   = (const float*)d_in[8];
    const float* Wr1   = (const float*)d_in[9];
    const float* br1   = (const float*)d_in[10];
    const float* att1  = (const float*)d_in[11];
    const float* bias1 = (const float*)d_in[12];
    _Float16* wt = (_Float16*)d_ws;   // 512 KB
    float* out = (float*)d_out;

    prep_weights<<<64, 256, 0, stream>>>(Wl0, Wr0, Wl1, Wr1, wt);
    gat_fused<<<NNODES / NB, 512, 0, stream>>>(x, bl0, br0, att0, bias0,
                                               bl1, br1, att1, bias1, wt, out);
}